// Round 2
// baseline (265.097 us; speedup 1.0000x reference)
//
#include <hip/hip_runtime.h>

typedef _Float16 f16;
typedef _Float16 f16x4 __attribute__((ext_vector_type(4)));
typedef _Float16 f16x8 __attribute__((ext_vector_type(8)));
typedef float f32x4 __attribute__((ext_vector_type(4)));

constexpr int NN = 50000;
constexpr int NE = 800000;
constexpr int MP = 50048;   // 391 * 128 (padded row count)
constexpr int CAP = 64;     // bucket capacity per node (Poisson(16) tail ~1e-18)

__global__ void zero_cnt(int* __restrict__ cnt) {
  int i = blockIdx.x * 256 + threadIdx.x;
  if (i < NN) cnt[i] = 0;
}

// fp32 x [50000][128] -> f16 xh [MP][128], pad rows zeroed
__global__ void conv_x(const float* __restrict__ x, f16* __restrict__ xh) {
  int i = blockIdx.x * 256 + threadIdx.x;  // 8 elements per thread
  if (i >= MP * 128 / 8) return;
  int row = i >> 4;  // 16 chunks of 8 per 128-wide row
  f16x8 o;
  if (row < NN) {
    const float4* p = (const float4*)(x + (size_t)i * 8);
    float4 a = p[0], b = p[1];
    o = f16x8{(f16)a.x, (f16)a.y, (f16)a.z, (f16)a.w,
              (f16)b.x, (f16)b.y, (f16)b.z, (f16)b.w};
  } else {
    o = f16x8{0, 0, 0, 0, 0, 0, 0, 0};
  }
  *(f16x8*)(xh + (size_t)i * 8) = o;
}

// W [K][N] fp32 -> Wt [N][K] f16 (transpose + convert; small, perf-irrelevant)
__global__ void conv_w(const float* __restrict__ W, f16* __restrict__ Wt, int K, int N) {
  int i = blockIdx.x * 256 + threadIdx.x;
  if (i >= N * K) return;
  int n = i / K, k = i - n * K;
  Wt[i] = (f16)W[(size_t)k * N + n];
}

// build per-dst buckets: one int atomic per edge
__global__ void scatter_edges(const int* __restrict__ src, const int* __restrict__ dst,
                              int* __restrict__ cnt, int* __restrict__ bucket) {
  int e = blockIdx.x * 256 + threadIdx.x;
  if (e >= NE) return;
  int d = dst[e];
  int slot = atomicAdd(&cnt[d], 1);
  if (slot < CAP) bucket[(size_t)d * CAP + slot] = src[e];
}

// one wave per node: sum h[src] rows (f16 in, fp32 acc), write h_agg f16
__global__ __launch_bounds__(256) void agg_kernel(const f16* __restrict__ h,
    const int* __restrict__ cnt, const int* __restrict__ bucket,
    f16* __restrict__ hagg) {
  int wid = (blockIdx.x * 256 + threadIdx.x) >> 6;
  int l = threadIdx.x & 63;
  if (wid >= NN) return;
  int deg = cnt[wid];
  if (deg > CAP) deg = CAP;
  const int* bl = bucket + (size_t)wid * CAP;
  float a0 = 0.f, a1 = 0.f, a2 = 0.f, a3 = 0.f;
  for (int e = 0; e < deg; ++e) {
    int s = bl[e];
    f16x4 v = *(const f16x4*)(h + (size_t)s * 256 + l * 4);
    a0 += (float)v[0]; a1 += (float)v[1]; a2 += (float)v[2]; a3 += (float)v[3];
  }
  f16x4 o = {(f16)a0, (f16)a1, (f16)a2, (f16)a3};
  *(f16x4*)(hagg + (size_t)wid * 256 + l * 4) = o;
}

// C[M][N] = act(A[M][K] @ Wt[N][K]^T + bias). BM=BN=128, BK=64, 4 waves.
template<int K, int N, bool RELU, bool OUT_F32>
__global__ __launch_bounds__(256, 2) void gemm_kernel(
    const f16* __restrict__ A, const f16* __restrict__ Wt,
    const float* __restrict__ bias, void* __restrict__ Cout, int Mvalid) {
  constexpr int LDT = 72;  // f16 row stride: 144 B -> banks spread 4r mod 32, 16B-aligned
  __shared__ f16 As[128 * LDT];
  __shared__ f16 Bs[128 * LDT];
  const int m0 = blockIdx.x * 128;
  const int n0 = blockIdx.y * 128;
  const int t = threadIdx.x;
  const int w = t >> 6, l = t & 63;
  const int wm = (w >> 1) * 64, wn = (w & 1) * 64;
  const int lg = l >> 4, lr = l & 15;
  f32x4 acc[4][4] = {};
  for (int kt = 0; kt < K; kt += 64) {
    #pragma unroll
    for (int it = 0; it < 4; ++it) {
      int chunk = it * 256 + t;
      int r = chunk >> 3, c8 = (chunk & 7) * 8;
      *(uint4*)(&As[r * LDT + c8]) = *(const uint4*)(A + (size_t)(m0 + r) * K + kt + c8);
      *(uint4*)(&Bs[r * LDT + c8]) = *(const uint4*)(Wt + (size_t)(n0 + r) * K + kt + c8);
    }
    __syncthreads();
    #pragma unroll
    for (int kk = 0; kk < 64; kk += 32) {
      f16x8 af[4], bf[4];
      #pragma unroll
      for (int i = 0; i < 4; ++i) {
        // operand element j: k = 16*(j>=4) + 4*(lane>>4) + (j&3)
        const f16* p = &As[(wm + i * 16 + lr) * LDT + kk + lg * 4];
        f16x4 alo = *(const f16x4*)p;
        f16x4 ahi = *(const f16x4*)(p + 16);
        af[i] = __builtin_shufflevector(alo, ahi, 0, 1, 2, 3, 4, 5, 6, 7);
        const f16* q = &Bs[(wn + i * 16 + lr) * LDT + kk + lg * 4];
        f16x4 blo = *(const f16x4*)q;
        f16x4 bhi = *(const f16x4*)(q + 16);
        bf[i] = __builtin_shufflevector(blo, bhi, 0, 1, 2, 3, 4, 5, 6, 7);
      }
      #pragma unroll
      for (int i = 0; i < 4; ++i)
        #pragma unroll
        for (int j = 0; j < 4; ++j)
          acc[i][j] = __builtin_amdgcn_mfma_f32_16x16x32_f16(af[i], bf[j], acc[i][j], 0, 0, 0);
    }
    __syncthreads();
  }
  // epilogue: C/D layout col = lane&15, row = (lane>>4)*4 + reg
  #pragma unroll
  for (int i = 0; i < 4; ++i) {
    #pragma unroll
    for (int j = 0; j < 4; ++j) {
      int n = n0 + wn + j * 16 + lr;
      float bv = bias[n];
      #pragma unroll
      for (int r = 0; r < 4; ++r) {
        int m = m0 + wm + i * 16 + lg * 4 + r;
        float v = acc[i][j][r] + bv;
        if (RELU) v = v > 0.f ? v : 0.f;
        if (OUT_F32) {
          if (m < Mvalid) ((float*)Cout)[(size_t)m * N + n] = v;
        } else {
          ((f16*)Cout)[(size_t)m * N + n] = (f16)v;
        }
      }
    }
  }
}

extern "C" void kernel_launch(void* const* d_in, const int* in_sizes, int n_in,
                              void* d_out, int out_size, void* d_ws, size_t ws_size,
                              hipStream_t stream) {
  const float* x   = (const float*)d_in[0];
  const int*   ei  = (const int*)d_in[1];   // [2][NE]: row0 = src, row1 = dst
  const float* W1i = (const float*)d_in[2];
  const float* b1i = (const float*)d_in[3];
  const float* W2i = (const float*)d_in[4];
  const float* b2i = (const float*)d_in[5];
  const float* W1f = (const float*)d_in[6];
  const float* b1f = (const float*)d_in[7];
  const float* W2f = (const float*)d_in[8];
  const float* b2f = (const float*)d_in[9];
  float* out = (float*)d_out;

  char* ws = (char*)d_ws;
  size_t off = 0;
  auto alloc = [&](size_t bytes) -> void* {
    void* p = ws + off;
    off += (bytes + 255) & ~(size_t)255;
    return p;
  };
  f16* xh    = (f16*)alloc((size_t)MP * 128 * 2);
  f16* w1it  = (f16*)alloc((size_t)512 * 128 * 2);
  f16* w2it  = (f16*)alloc((size_t)256 * 512 * 2);
  f16* w1ft  = (f16*)alloc((size_t)512 * 256 * 2);
  f16* w2ft  = (f16*)alloc((size_t)128 * 512 * 2);
  f16* hid   = (f16*)alloc((size_t)MP * 512 * 2);  // reused for hidden1 and hidden2
  f16* h     = (f16*)alloc((size_t)MP * 256 * 2);
  f16* hagg  = (f16*)alloc((size_t)MP * 256 * 2);
  int* cnt   = (int*)alloc((size_t)NN * 4);
  int* bucket= (int*)alloc((size_t)NN * CAP * 4);

  zero_cnt<<<(NN + 255) / 256, 256, 0, stream>>>(cnt);
  conv_x<<<(MP * 128 / 8 + 255) / 256, 256, 0, stream>>>(x, xh);
  conv_w<<<(512 * 128 + 255) / 256, 256, 0, stream>>>(W1i, w1it, 128, 512);
  conv_w<<<(256 * 512 + 255) / 256, 256, 0, stream>>>(W2i, w2it, 512, 256);
  conv_w<<<(512 * 256 + 255) / 256, 256, 0, stream>>>(W1f, w1ft, 256, 512);
  conv_w<<<(128 * 512 + 255) / 256, 256, 0, stream>>>(W2f, w2ft, 512, 128);
  scatter_edges<<<(NE + 255) / 256, 256, 0, stream>>>(ei, ei + NE, cnt, bucket);

  gemm_kernel<128, 512, true,  false><<<dim3(MP / 128, 4), 256, 0, stream>>>(xh,   w1it, b1i, hid, MP);
  gemm_kernel<512, 256, false, false><<<dim3(MP / 128, 2), 256, 0, stream>>>(hid,  w2it, b2i, h,   MP);
  agg_kernel<<<(NN * 64) / 256, 256, 0, stream>>>(h, cnt, bucket, hagg);
  gemm_kernel<256, 512, true,  false><<<dim3(MP / 128, 4), 256, 0, stream>>>(hagg, w1ft, b1f, hid, MP);
  gemm_kernel<512, 128, false, true ><<<dim3(MP / 128, 1), 256, 0, stream>>>(hid,  w2ft, b2f, out, NN);
}

// Round 3
// 230.368 us; speedup vs baseline: 1.1508x; 1.1508x over previous
//
#include <hip/hip_runtime.h>

typedef _Float16 f16;
typedef _Float16 f16x4 __attribute__((ext_vector_type(4)));
typedef _Float16 f16x8 __attribute__((ext_vector_type(8)));
typedef float f32x4 __attribute__((ext_vector_type(4)));

constexpr int NN = 50000;
constexpr int NE = 800000;
constexpr int MP = 50048;   // 391 * 128 (padded row count)
constexpr int CAP = 64;     // bucket capacity per node (Poisson(16) tail ~1e-18)

// fp32 x [50000][128] -> f16 xh [MP][128], pad rows zeroed
__global__ void conv_x(const float* __restrict__ x, f16* __restrict__ xh) {
  int i = blockIdx.x * 256 + threadIdx.x;  // 8 elements per thread
  if (i >= MP * 128 / 8) return;
  int row = i >> 4;  // 16 chunks of 8 per 128-wide row
  f16x8 o;
  if (row < NN) {
    const float4* p = (const float4*)(x + (size_t)i * 8);
    float4 a = p[0], b = p[1];
    o = f16x8{(f16)a.x, (f16)a.y, (f16)a.z, (f16)a.w,
              (f16)b.x, (f16)b.y, (f16)b.z, (f16)b.w};
  } else {
    o = f16x8{0, 0, 0, 0, 0, 0, 0, 0};
  }
  *(f16x8*)(xh + (size_t)i * 8) = o;
}

// all four weight transposes in one launch: W [K][N] fp32 -> Wt [N][K] f16
__global__ void conv_w_all(const float* __restrict__ W1i, const float* __restrict__ W2i,
                           const float* __restrict__ W1f, const float* __restrict__ W2f,
                           f16* __restrict__ w1it, f16* __restrict__ w2it,
                           f16* __restrict__ w1ft, f16* __restrict__ w2ft) {
  int i = blockIdx.x * 256 + threadIdx.x;  // total 393216
  const float* W; f16* Wt; int K, N, idx;
  if (i < 65536)       { W = W1i; Wt = w1it; K = 128; N = 512; idx = i; }
  else if (i < 196608) { W = W2i; Wt = w2it; K = 512; N = 256; idx = i - 65536; }
  else if (i < 327680) { W = W1f; Wt = w1ft; K = 256; N = 512; idx = i - 196608; }
  else                 { W = W2f; Wt = w2ft; K = 512; N = 128; idx = i - 327680; }
  int n = idx / K, k = idx - n * K;
  Wt[idx] = (f16)W[(size_t)k * N + n];
}

// build per-dst buckets: one int atomic per edge
__global__ void scatter_edges(const int* __restrict__ src, const int* __restrict__ dst,
                              int* __restrict__ cnt, int* __restrict__ bucket) {
  int e = blockIdx.x * 256 + threadIdx.x;
  if (e >= NE) return;
  int d = dst[e];
  int slot = atomicAdd(&cnt[d], 1);
  if (slot < CAP) bucket[(size_t)d * CAP + slot] = src[e];
}

// one wave per node: sum h[src] rows (f16 in, fp32 acc), write h_agg f16.
// Lane-parallel bucket read (lane l holds slot l) + 8-deep gather MLP.
__global__ __launch_bounds__(256) void agg_kernel(const f16* __restrict__ h,
    const int* __restrict__ cnt, const int* __restrict__ bucket,
    f16* __restrict__ hagg) {
  int wid = (blockIdx.x * 256 + threadIdx.x) >> 6;
  int l = threadIdx.x & 63;
  if (wid >= NN) return;
  int deg = cnt[wid];
  if (deg > CAP) deg = CAP;
  int s_all = bucket[(size_t)wid * CAP + l];  // slots >= deg unread via shfl
  const f16* hb = h + l * 4;
  float a0 = 0.f, a1 = 0.f, a2 = 0.f, a3 = 0.f;
  int e = 0;
  for (; e + 8 <= deg; e += 8) {
    f16x4 v[8];
    #pragma unroll
    for (int u = 0; u < 8; ++u) {
      int s = __shfl(s_all, e + u);
      v[u] = *(const f16x4*)(hb + (size_t)s * 256);
    }
    #pragma unroll
    for (int u = 0; u < 8; ++u) {
      a0 += (float)v[u][0]; a1 += (float)v[u][1];
      a2 += (float)v[u][2]; a3 += (float)v[u][3];
    }
  }
  for (; e + 2 <= deg; e += 2) {
    int s0 = __shfl(s_all, e), s1 = __shfl(s_all, e + 1);
    f16x4 v0 = *(const f16x4*)(hb + (size_t)s0 * 256);
    f16x4 v1 = *(const f16x4*)(hb + (size_t)s1 * 256);
    a0 += (float)v0[0] + (float)v1[0]; a1 += (float)v0[1] + (float)v1[1];
    a2 += (float)v0[2] + (float)v1[2]; a3 += (float)v0[3] + (float)v1[3];
  }
  if (e < deg) {
    int s = __shfl(s_all, e);
    f16x4 v = *(const f16x4*)(hb + (size_t)s * 256);
    a0 += (float)v[0]; a1 += (float)v[1]; a2 += (float)v[2]; a3 += (float)v[3];
  }
  f16x4 o = {(f16)a0, (f16)a1, (f16)a2, (f16)a3};
  *(f16x4*)(hagg + (size_t)wid * 256 + l * 4) = o;
}

// C[M][N] = act(A[M][K] @ Wt[N][K]^T + bias). BM=BN=128, BK=64, 4 waves.
template<int K, int N, bool RELU, bool OUT_F32>
__global__ __launch_bounds__(256, 2) void gemm_kernel(
    const f16* __restrict__ A, const f16* __restrict__ Wt,
    const float* __restrict__ bias, void* __restrict__ Cout, int Mvalid) {
  constexpr int LDT = 72;  // f16 row stride: 144 B -> banks spread 4r mod 32, 16B-aligned
  __shared__ f16 As[128 * LDT];
  __shared__ f16 Bs[128 * LDT];
  const int m0 = blockIdx.x * 128;
  const int n0 = blockIdx.y * 128;
  const int t = threadIdx.x;
  const int w = t >> 6, l = t & 63;
  const int wm = (w >> 1) * 64, wn = (w & 1) * 64;
  const int lg = l >> 4, lr = l & 15;
  f32x4 acc[4][4] = {};
  for (int kt = 0; kt < K; kt += 64) {
    #pragma unroll
    for (int it = 0; it < 4; ++it) {
      int chunk = it * 256 + t;
      int r = chunk >> 3, c8 = (chunk & 7) * 8;
      *(uint4*)(&As[r * LDT + c8]) = *(const uint4*)(A + (size_t)(m0 + r) * K + kt + c8);
      *(uint4*)(&Bs[r * LDT + c8]) = *(const uint4*)(Wt + (size_t)(n0 + r) * K + kt + c8);
    }
    __syncthreads();
    #pragma unroll
    for (int kk = 0; kk < 64; kk += 32) {
      f16x8 af[4], bf[4];
      #pragma unroll
      for (int i = 0; i < 4; ++i) {
        // operand element j: k = 16*(j>=4) + 4*(lane>>4) + (j&3)
        const f16* p = &As[(wm + i * 16 + lr) * LDT + kk + lg * 4];
        f16x4 alo = *(const f16x4*)p;
        f16x4 ahi = *(const f16x4*)(p + 16);
        af[i] = __builtin_shufflevector(alo, ahi, 0, 1, 2, 3, 4, 5, 6, 7);
        const f16* q = &Bs[(wn + i * 16 + lr) * LDT + kk + lg * 4];
        f16x4 blo = *(const f16x4*)q;
        f16x4 bhi = *(const f16x4*)(q + 16);
        bf[i] = __builtin_shufflevector(blo, bhi, 0, 1, 2, 3, 4, 5, 6, 7);
      }
      #pragma unroll
      for (int i = 0; i < 4; ++i)
        #pragma unroll
        for (int j = 0; j < 4; ++j)
          acc[i][j] = __builtin_amdgcn_mfma_f32_16x16x32_f16(af[i], bf[j], acc[i][j], 0, 0, 0);
    }
    __syncthreads();
  }
  // epilogue: C/D layout col = lane&15, row = (lane>>4)*4 + reg
  #pragma unroll
  for (int i = 0; i < 4; ++i) {
    #pragma unroll
    for (int j = 0; j < 4; ++j) {
      int n = n0 + wn + j * 16 + lr;
      float bv = bias[n];
      #pragma unroll
      for (int r = 0; r < 4; ++r) {
        int m = m0 + wm + i * 16 + lg * 4 + r;
        float v = acc[i][j][r] + bv;
        if (RELU) v = v > 0.f ? v : 0.f;
        if (OUT_F32) {
          if (m < Mvalid) ((float*)Cout)[(size_t)m * N + n] = v;
        } else {
          ((f16*)Cout)[(size_t)m * N + n] = (f16)v;
        }
      }
    }
  }
}

extern "C" void kernel_launch(void* const* d_in, const int* in_sizes, int n_in,
                              void* d_out, int out_size, void* d_ws, size_t ws_size,
                              hipStream_t stream) {
  const float* x   = (const float*)d_in[0];
  const int*   ei  = (const int*)d_in[1];   // [2][NE]: row0 = src, row1 = dst
  const float* W1i = (const float*)d_in[2];
  const float* b1i = (const float*)d_in[3];
  const float* W2i = (const float*)d_in[4];
  const float* b2i = (const float*)d_in[5];
  const float* W1f = (const float*)d_in[6];
  const float* b1f = (const float*)d_in[7];
  const float* W2f = (const float*)d_in[8];
  const float* b2f = (const float*)d_in[9];
  float* out = (float*)d_out;

  char* ws = (char*)d_ws;
  size_t off = 0;
  auto alloc = [&](size_t bytes) -> void* {
    void* p = ws + off;
    off += (bytes + 255) & ~(size_t)255;
    return p;
  };
  f16* xh    = (f16*)alloc((size_t)MP * 128 * 2);
  f16* w1it  = (f16*)alloc((size_t)512 * 128 * 2);
  f16* w2it  = (f16*)alloc((size_t)256 * 512 * 2);
  f16* w1ft  = (f16*)alloc((size_t)512 * 256 * 2);
  f16* w2ft  = (f16*)alloc((size_t)128 * 512 * 2);
  f16* hid   = (f16*)alloc((size_t)MP * 512 * 2);  // reused for hidden1 and hidden2
  f16* h     = (f16*)alloc((size_t)MP * 256 * 2);
  f16* hagg  = (f16*)alloc((size_t)MP * 256 * 2);
  int* cnt   = (int*)alloc((size_t)NN * 4);
  int* bucket= (int*)alloc((size_t)NN * CAP * 4);

  hipMemsetAsync(cnt, 0, (size_t)NN * 4, stream);
  conv_x<<<(MP * 128 / 8 + 255) / 256, 256, 0, stream>>>(x, xh);
  conv_w_all<<<393216 / 256, 256, 0, stream>>>(W1i, W2i, W1f, W2f, w1it, w2it, w1ft, w2ft);
  scatter_edges<<<(NE + 255) / 256, 256, 0, stream>>>(ei, ei + NE, cnt, bucket);

  gemm_kernel<128, 512, true,  false><<<dim3(MP / 128, 4), 256, 0, stream>>>(xh,   w1it, b1i, hid, MP);
  gemm_kernel<512, 256, false, false><<<dim3(MP / 128, 2), 256, 0, stream>>>(hid,  w2it, b2i, h,   MP);
  agg_kernel<<<(NN * 64) / 256, 256, 0, stream>>>(h, cnt, bucket, hagg);
  gemm_kernel<256, 512, true,  false><<<dim3(MP / 128, 4), 256, 0, stream>>>(hagg, w1ft, b1f, hid, MP);
  gemm_kernel<512, 128, false, true ><<<dim3(MP / 128, 1), 256, 0, stream>>>(hid,  w2ft, b2f, out, NN);
}